// Round 1
// baseline (567.448 us; speedup 1.0000x reference)
//
#include <hip/hip_runtime.h>

typedef __attribute__((ext_vector_type(4))) float f32x4;
typedef __attribute__((ext_vector_type(8))) short bf16x8;

#define DEV __device__ __forceinline__

DEV unsigned short f2bf(float f) {            // RTNE f32 -> bf16
  unsigned u = __float_as_uint(f);
  unsigned r = (u + 0x7FFFu + ((u >> 16) & 1u)) >> 16;
  return (unsigned short)r;
}
DEV float bf2f(unsigned short h) { return __uint_as_float(((unsigned)h) << 16); }

typedef __attribute__((address_space(1))) void gas_t;
typedef __attribute__((address_space(3))) void las_t;
DEV void async16(void* lds, const void* g) {
  __builtin_amdgcn_global_load_lds((gas_t*)g, (las_t*)lds, 16, 0, 0);
}

// ---------------- elementwise cast: f32 -> bf16, 8 elems/thread ----------------
__global__ void cast_x(const float* __restrict__ x, unsigned short* __restrict__ y, int n8) {
  int idx = blockIdx.x * blockDim.x + threadIdx.x;
  int stride = gridDim.x * blockDim.x;
  for (; idx < n8; idx += stride) {
    const float4* p = (const float4*)(x + (size_t)idx * 8);
    float4 v0 = p[0], v1 = p[1];
    bf16x8 o;
    o[0] = (short)f2bf(v0.x); o[1] = (short)f2bf(v0.y);
    o[2] = (short)f2bf(v0.z); o[3] = (short)f2bf(v0.w);
    o[4] = (short)f2bf(v1.x); o[5] = (short)f2bf(v1.y);
    o[6] = (short)f2bf(v1.z); o[7] = (short)f2bf(v1.w);
    *(bf16x8*)(y + (size_t)idx * 8) = o;
  }
}

// ---------------- transpose + cast: W[K][N] f32 -> Wt[N][K] bf16 ----------------
__global__ void transpose_cast(const float* __restrict__ W, unsigned short* __restrict__ Wt,
                               int Kdim, int Nw) {
  __shared__ float tile[32][33];
  int n0 = blockIdx.x * 32, k0 = blockIdx.y * 32;
  int tx = threadIdx.x, ty = threadIdx.y;
#pragma unroll
  for (int r = ty; r < 32; r += 8)
    tile[r][tx] = W[(size_t)(k0 + r) * Nw + n0 + tx];
  __syncthreads();
#pragma unroll
  for (int r = ty; r < 32; r += 8)
    Wt[(size_t)(n0 + r) * Kdim + k0 + tx] = f2bf(tile[tx][r]);
}

// ---------------- GEMM (m97 structure): A[M][K] x Bt[N][K] -------------------
// EPI==0: write f32 C[M][Nr].  EPI==1: scatter QKV (N=3072: 2048 Q | 512 K | 512 V^T)
template <int EPI>
__global__ __launch_bounds__(256, 2)
void gemm_bt(const unsigned short* __restrict__ A, const unsigned short* __restrict__ Bt,
             int Kr, float* __restrict__ Cf, int Nr,
             unsigned short* __restrict__ Qn, unsigned short* __restrict__ Kn,
             unsigned short* __restrict__ Vt) {
  __shared__ __align__(16) unsigned short lsA[128 * 32];
  __shared__ __align__(16) unsigned short lsB[128 * 32];
  const int t = threadIdx.x;
  const int lane = t & 63;
  const int w = t >> 6, wr = w >> 1, wc = w & 1;
  const int lo = lane & 15, hi = lane >> 4;
  const int m0 = blockIdx.y * 128, n0 = blockIdx.x * 128;

  const int c0 = t, c1 = t + 256;  // 16B chunk ids of the 128x32 bf16 tile
  const unsigned short* gA0 = A + (size_t)(m0 + (c0 >> 2)) * Kr + (c0 & 3) * 8;
  const unsigned short* gA1 = A + (size_t)(m0 + (c1 >> 2)) * Kr + (c1 & 3) * 8;
  const unsigned short* gB0 = Bt + (size_t)(n0 + (c0 >> 2)) * Kr + (c0 & 3) * 8;
  const unsigned short* gB1 = Bt + (size_t)(n0 + (c1 >> 2)) * Kr + (c1 & 3) * 8;
  unsigned short* lA0 = lsA + c0 * 8;
  unsigned short* lA1 = lsA + c1 * 8;
  unsigned short* lB0 = lsB + c0 * 8;
  unsigned short* lB1 = lsB + c1 * 8;

  f32x4 acc[4][4] = {};

  for (int kt = 0; kt < Kr; kt += 32) {
    async16(lA0, gA0 + kt);
    async16(lA1, gA1 + kt);
    async16(lB0, gB0 + kt);
    async16(lB1, gB1 + kt);
    __syncthreads();  // drains vmcnt -> LDS tile ready
    bf16x8 af[4], bfr[4];
#pragma unroll
    for (int i = 0; i < 4; ++i) {
      af[i]  = *(const bf16x8*)&lsA[(wr * 64 + i * 16 + lo) * 32 + hi * 8];
      bfr[i] = *(const bf16x8*)&lsB[(wc * 64 + i * 16 + lo) * 32 + hi * 8];
    }
#pragma unroll
    for (int mi = 0; mi < 4; ++mi)
#pragma unroll
      for (int ni = 0; ni < 4; ++ni)
        acc[mi][ni] = __builtin_amdgcn_mfma_f32_16x16x32_bf16(af[mi], bfr[ni], acc[mi][ni], 0, 0, 0);
    __syncthreads();  // all reads done before next stage overwrites
  }

#pragma unroll
  for (int mi = 0; mi < 4; ++mi)
#pragma unroll
    for (int ni = 0; ni < 4; ++ni)
#pragma unroll
      for (int i = 0; i < 4; ++i) {
        int gm = m0 + wr * 64 + mi * 16 + hi * 4 + i;
        int gn = n0 + wc * 64 + ni * 16 + lo;
        float v = acc[mi][ni][i];
        if (EPI == 0) {
          Cf[(size_t)gm * Nr + gn] = v;
        } else {
          unsigned short bv = f2bf(v);
          int bb = gm >> 11, tt = gm & 2047;
          if (gn < 2048) {                      // Q: [b][h][t][d]
            int hh = gn >> 7, dd = gn & 127;
            Qn[(((size_t)bb * 16 + hh) * 2048 + tt) * 128 + dd] = bv;
          } else if (gn < 2560) {               // K: [b][hkv][t][d]
            int g2 = gn - 2048, hh = g2 >> 7, dd = g2 & 127;
            Kn[(((size_t)bb * 4 + hh) * 2048 + tt) * 128 + dd] = bv;
          } else {                              // V^T: [b][hkv][d][t]
            int g2 = gn - 2560, hh = g2 >> 7, dd = g2 & 127;
            Vt[(((size_t)bb * 4 + hh) * 128 + dd) * 2048 + tt] = bv;
          }
        }
      }
}

// ---------------- QK RMS-norm (in place), folds 1/sqrt(D) into Q --------------
__global__ __launch_bounds__(256)
void qk_norm(unsigned short* __restrict__ Qn, unsigned short* __restrict__ Kn, float qscale) {
  int row = blockIdx.x * 4 + (threadIdx.x >> 6);
  int lane = threadIdx.x & 63;
  unsigned short* base;
  float scl;
  if (row < 65536) { base = Qn + (size_t)row * 128; scl = qscale; }
  else             { base = Kn + (size_t)(row - 65536) * 128; scl = 1.0f; }
  unsigned v = *(const unsigned*)(base + lane * 2);
  float a = bf2f((unsigned short)(v & 0xffffu));
  float b = bf2f((unsigned short)(v >> 16));
  float ss = a * a + b * b;
#pragma unroll
  for (int m = 1; m < 64; m <<= 1) ss += __shfl_xor(ss, m, 64);
  float r = rsqrtf(ss * (1.0f / 128.0f) + 1e-6f) * scl;
  *(unsigned*)(base + lane * 2) = ((unsigned)f2bf(b * r) << 16) | (unsigned)f2bf(a * r);
}

// ---------------- flash attention: 4 waves x 32 q-rows, KV from global --------
__global__ __launch_bounds__(256, 1)
void attn(const unsigned short* __restrict__ Q, const unsigned short* __restrict__ Kk,
          const unsigned short* __restrict__ Vt, unsigned short* __restrict__ AO) {
  const int bh = blockIdx.y;          // b*16 + h
  const int b = bh >> 4, h = bh & 15;
  const int hkv = h >> 2;             // jnp.repeat(·,4): head h uses kv head h/4
  const int w = threadIdx.x >> 6, lane = threadIdx.x & 63;
  const int lo = lane & 15, hi = lane >> 4;
  const unsigned short* Qb = Q  + (size_t)bh * 2048 * 128;
  const unsigned short* Kb = Kk + (size_t)(b * 4 + hkv) * 2048 * 128;
  const unsigned short* Vb = Vt + (size_t)(b * 4 + hkv) * 128 * 2048;
  const int q0 = blockIdx.x * 128 + w * 32;

  __shared__ __align__(16) unsigned short Plds[4][32][64];

  bf16x8 qf[2][4];
#pragma unroll
  for (int qm = 0; qm < 2; ++qm)
#pragma unroll
    for (int kd = 0; kd < 4; ++kd)
      qf[qm][kd] = *(const bf16x8*)&Qb[(size_t)(q0 + qm * 16 + lo) * 128 + kd * 32 + hi * 8];

  f32x4 Oa[2][8] = {};
  float mrow[2][4], srow[2][4];
#pragma unroll
  for (int qm = 0; qm < 2; ++qm)
#pragma unroll
    for (int i = 0; i < 4; ++i) { mrow[qm][i] = -1e30f; srow[qm][i] = 0.f; }

  const float LOG2E = 1.4426950408889634f;
  for (int kt = 0; kt < 2048; kt += 64) {
    f32x4 S[2][4] = {};
#pragma unroll
    for (int kn = 0; kn < 4; ++kn) {
      bf16x8 kf[4];
#pragma unroll
      for (int kd = 0; kd < 4; ++kd)
        kf[kd] = *(const bf16x8*)&Kb[(size_t)(kt + kn * 16 + lo) * 128 + kd * 32 + hi * 8];
#pragma unroll
      for (int qm = 0; qm < 2; ++qm)
#pragma unroll
        for (int kd = 0; kd < 4; ++kd)
          S[qm][kn] = __builtin_amdgcn_mfma_f32_16x16x32_bf16(qf[qm][kd], kf[kd], S[qm][kn], 0, 0, 0);
    }
    // online softmax: row = qm*16 + hi*4 + i, col = kn*16 + lo
#pragma unroll
    for (int qm = 0; qm < 2; ++qm) {
      float al[4];
#pragma unroll
      for (int i = 0; i < 4; ++i) {
        float mx = fmaxf(fmaxf(S[qm][0][i], S[qm][1][i]), fmaxf(S[qm][2][i], S[qm][3][i]));
#pragma unroll
        for (int d = 1; d < 16; d <<= 1) mx = fmaxf(mx, __shfl_xor(mx, d, 64));
        float mnew = fmaxf(mrow[qm][i], mx);
        al[i] = exp2f((mrow[qm][i] - mnew) * LOG2E);
        mrow[qm][i] = mnew;
        float rs = 0.f;
#pragma unroll
        for (int kn = 0; kn < 4; ++kn) {
          float p = exp2f((S[qm][kn][i] - mnew) * LOG2E);
          S[qm][kn][i] = p;
          rs += p;
        }
#pragma unroll
        for (int d = 1; d < 16; d <<= 1) rs += __shfl_xor(rs, d, 64);
        srow[qm][i] = srow[qm][i] * al[i] + rs;
      }
#pragma unroll
      for (int dn = 0; dn < 8; ++dn)
#pragma unroll
        for (int i = 0; i < 4; ++i) Oa[qm][dn][i] *= al[i];
#pragma unroll
      for (int kn = 0; kn < 4; ++kn)
#pragma unroll
        for (int i = 0; i < 4; ++i)
          Plds[w][qm * 16 + hi * 4 + i][kn * 16 + lo] = f2bf(S[qm][kn][i]);
    }
    // PV: A = P from LDS, B = V^T rows (contiguous along keys)
#pragma unroll
    for (int ks = 0; ks < 2; ++ks) {
      bf16x8 pf[2];
#pragma unroll
      for (int qm = 0; qm < 2; ++qm)
        pf[qm] = *(const bf16x8*)&Plds[w][qm * 16 + lo][ks * 32 + hi * 8];
#pragma unroll
      for (int dn = 0; dn < 8; ++dn) {
        bf16x8 vf = *(const bf16x8*)&Vb[(size_t)(dn * 16 + lo) * 2048 + kt + ks * 32 + hi * 8];
#pragma unroll
        for (int qm = 0; qm < 2; ++qm)
          Oa[qm][dn] = __builtin_amdgcn_mfma_f32_16x16x32_bf16(pf[qm], vf, Oa[qm][dn], 0, 0, 0);
      }
    }
  }
#pragma unroll
  for (int qm = 0; qm < 2; ++qm)
#pragma unroll
    for (int dn = 0; dn < 8; ++dn)
#pragma unroll
      for (int i = 0; i < 4; ++i) {
        int tt = q0 + qm * 16 + hi * 4 + i;
        float o = Oa[qm][dn][i] / srow[qm][i];
        AO[((size_t)(b * 2048 + tt)) * 2048 + h * 128 + dn * 16 + lo] = f2bf(o);
      }
}

// ------------------------------- launcher -------------------------------------
extern "C" void kernel_launch(void* const* d_in, const int* in_sizes, int n_in,
                              void* d_out, int out_size, void* d_ws, size_t ws_size,
                              hipStream_t stream) {
  const float* x_q = (const float*)d_in[0];
  const float* Wq  = (const float*)d_in[1];
  const float* Wk  = (const float*)d_in[2];
  const float* Wv  = (const float*)d_in[3];
  const float* Wo  = (const float*)d_in[4];
  float* out = (float*)d_out;

  char* ws = (char*)d_ws;
  unsigned short* Xb    = (unsigned short*)(ws);             // 16.8 MB (reused as AO)
  unsigned short* WqkvT = (unsigned short*)(ws + 16777216);  // 12.6 MB
  unsigned short* WoT   = (unsigned short*)(ws + 29360128);  //  8.4 MB
  unsigned short* Qn    = (unsigned short*)(ws + 37748736);  // 16.8 MB
  unsigned short* Kn    = (unsigned short*)(ws + 54525952);  //  4.2 MB
  unsigned short* Vt    = (unsigned short*)(ws + 58720256);  //  4.2 MB
  unsigned short* AO    = Xb;                                // aliases Xb (dead after GEMM1)

  cast_x<<<2048, 256, 0, stream>>>(x_q, Xb, (4096 * 2048) / 8);
  transpose_cast<<<dim3(2048 / 32, 2048 / 32), dim3(32, 8), 0, stream>>>(Wq, WqkvT, 2048, 2048);
  transpose_cast<<<dim3(512 / 32, 2048 / 32), dim3(32, 8), 0, stream>>>(Wk, WqkvT + 2048 * 2048, 2048, 512);
  transpose_cast<<<dim3(512 / 32, 2048 / 32), dim3(32, 8), 0, stream>>>(Wv, WqkvT + 2560 * 2048, 2048, 512);
  transpose_cast<<<dim3(2048 / 32, 2048 / 32), dim3(32, 8), 0, stream>>>(Wo, WoT, 2048, 2048);

  gemm_bt<1><<<dim3(3072 / 128, 4096 / 128), 256, 0, stream>>>(Xb, WqkvT, 2048, nullptr, 0, Qn, Kn, Vt);
  qk_norm<<<(65536 + 16384) / 4, 256, 0, stream>>>(Qn, Kn, 0.08838834764831845f);
  attn<<<dim3(2048 / 128, 32), 256, 0, stream>>>(Qn, Kn, Vt, AO);
  gemm_bt<0><<<dim3(2048 / 128, 4096 / 128), 256, 0, stream>>>(AO, WoT, 2048, out, 2048,
                                                               nullptr, nullptr, nullptr);
}

// Round 2
// 296.769 us; speedup vs baseline: 1.9121x; 1.9121x over previous
//
#include <hip/hip_runtime.h>

typedef __attribute__((ext_vector_type(4))) float f32x4;
typedef __attribute__((ext_vector_type(8))) short bf16x8;
typedef unsigned short ushort_t;

#define DEV __device__ __forceinline__

DEV unsigned short f2bf(float f) {            // RTNE f32 -> bf16
  unsigned u = __float_as_uint(f);
  unsigned r = (u + 0x7FFFu + ((u >> 16) & 1u)) >> 16;
  return (unsigned short)r;
}
DEV float bf2f(unsigned short h) { return __uint_as_float(((unsigned)h) << 16); }

typedef __attribute__((address_space(1))) void gas_t;
typedef __attribute__((address_space(3))) void las_t;
DEV void async16(void* lds, const void* g) {
  __builtin_amdgcn_global_load_lds((gas_t*)g, (las_t*)lds, 16, 0, 0);
}

// ---------------- elementwise cast: f32 -> bf16, 8 elems/thread ----------------
__global__ void cast_x(const float* __restrict__ x, unsigned short* __restrict__ y, int n8) {
  int idx = blockIdx.x * blockDim.x + threadIdx.x;
  int stride = gridDim.x * blockDim.x;
  for (; idx < n8; idx += stride) {
    const float4* p = (const float4*)(x + (size_t)idx * 8);
    float4 v0 = p[0], v1 = p[1];
    bf16x8 o;
    o[0] = (short)f2bf(v0.x); o[1] = (short)f2bf(v0.y);
    o[2] = (short)f2bf(v0.z); o[3] = (short)f2bf(v0.w);
    o[4] = (short)f2bf(v1.x); o[5] = (short)f2bf(v1.y);
    o[6] = (short)f2bf(v1.z); o[7] = (short)f2bf(v1.w);
    *(bf16x8*)(y + (size_t)idx * 8) = o;
  }
}

// ---------------- transpose + cast: W[K][N] f32 -> Wt[N][K] bf16 ----------------
__global__ void transpose_cast(const float* __restrict__ W, unsigned short* __restrict__ Wt,
                               int Kdim, int Nw) {
  __shared__ float tile[32][33];
  int n0 = blockIdx.x * 32, k0 = blockIdx.y * 32;
  int tx = threadIdx.x, ty = threadIdx.y;
#pragma unroll
  for (int r = ty; r < 32; r += 8)
    tile[r][tx] = W[(size_t)(k0 + r) * Nw + n0 + tx];
  __syncthreads();
#pragma unroll
  for (int r = ty; r < 32; r += 8)
    Wt[(size_t)(n0 + r) * Kdim + k0 + tx] = f2bf(tile[tx][r]);
}

// ---------------- GEMM (m97 structure): A[M][K] x Bt[N][K] -------------------
template <int EPI>
__global__ __launch_bounds__(256, 2)
void gemm_bt(const unsigned short* __restrict__ A, const unsigned short* __restrict__ Bt,
             int Kr, float* __restrict__ Cf, int Nr,
             unsigned short* __restrict__ Qn, unsigned short* __restrict__ Kn,
             unsigned short* __restrict__ Vt) {
  __shared__ __align__(16) unsigned short lsA[128 * 32];
  __shared__ __align__(16) unsigned short lsB[128 * 32];
  const int t = threadIdx.x;
  const int lane = t & 63;
  const int w = t >> 6, wr = w >> 1, wc = w & 1;
  const int lo = lane & 15, hi = lane >> 4;
  const int m0 = blockIdx.y * 128, n0 = blockIdx.x * 128;

  const int c0 = t, c1 = t + 256;
  const unsigned short* gA0 = A + (size_t)(m0 + (c0 >> 2)) * Kr + (c0 & 3) * 8;
  const unsigned short* gA1 = A + (size_t)(m0 + (c1 >> 2)) * Kr + (c1 & 3) * 8;
  const unsigned short* gB0 = Bt + (size_t)(n0 + (c0 >> 2)) * Kr + (c0 & 3) * 8;
  const unsigned short* gB1 = Bt + (size_t)(n0 + (c1 >> 2)) * Kr + (c1 & 3) * 8;
  unsigned short* lA0 = lsA + c0 * 8;
  unsigned short* lA1 = lsA + c1 * 8;
  unsigned short* lB0 = lsB + c0 * 8;
  unsigned short* lB1 = lsB + c1 * 8;

  f32x4 acc[4][4] = {};

  for (int kt = 0; kt < Kr; kt += 32) {
    async16(lA0, gA0 + kt);
    async16(lA1, gA1 + kt);
    async16(lB0, gB0 + kt);
    async16(lB1, gB1 + kt);
    __syncthreads();
    bf16x8 af[4], bfr[4];
#pragma unroll
    for (int i = 0; i < 4; ++i) {
      af[i]  = *(const bf16x8*)&lsA[(wr * 64 + i * 16 + lo) * 32 + hi * 8];
      bfr[i] = *(const bf16x8*)&lsB[(wc * 64 + i * 16 + lo) * 32 + hi * 8];
    }
#pragma unroll
    for (int mi = 0; mi < 4; ++mi)
#pragma unroll
      for (int ni = 0; ni < 4; ++ni)
        acc[mi][ni] = __builtin_amdgcn_mfma_f32_16x16x32_bf16(af[mi], bfr[ni], acc[mi][ni], 0, 0, 0);
    __syncthreads();
  }

#pragma unroll
  for (int mi = 0; mi < 4; ++mi)
#pragma unroll
    for (int ni = 0; ni < 4; ++ni)
#pragma unroll
      for (int i = 0; i < 4; ++i) {
        int gm = m0 + wr * 64 + mi * 16 + hi * 4 + i;
        int gn = n0 + wc * 64 + ni * 16 + lo;
        float v = acc[mi][ni][i];
        if (EPI == 0) {
          Cf[(size_t)gm * Nr + gn] = v;
        } else {
          unsigned short bv = f2bf(v);
          int bb = gm >> 11, tt = gm & 2047;
          if (gn < 2048) {                      // Q: [b][h][t][d]
            int hh = gn >> 7, dd = gn & 127;
            Qn[(((size_t)bb * 16 + hh) * 2048 + tt) * 128 + dd] = bv;
          } else if (gn < 2560) {               // K: [b][hkv][t][d]
            int g2 = gn - 2048, hh = g2 >> 7, dd = g2 & 127;
            Kn[(((size_t)bb * 4 + hh) * 2048 + tt) * 128 + dd] = bv;
          } else {                              // V^T: [b][hkv][d][t]
            int g2 = gn - 2560, hh = g2 >> 7, dd = g2 & 127;
            Vt[(((size_t)bb * 4 + hh) * 128 + dd) * 2048 + tt] = bv;
          }
        }
      }
}

// ---------------- QK RMS-norm (in place); Q also gets (1/sqrt(D))*log2(e) ------
__global__ __launch_bounds__(256)
void qk_norm(unsigned short* __restrict__ Qn, unsigned short* __restrict__ Kn, float qscale) {
  int row = blockIdx.x * 4 + (threadIdx.x >> 6);
  int lane = threadIdx.x & 63;
  unsigned short* base;
  float scl;
  if (row < 65536) { base = Qn + (size_t)row * 128; scl = qscale; }
  else             { base = Kn + (size_t)(row - 65536) * 128; scl = 1.0f; }
  unsigned v = *(const unsigned*)(base + lane * 2);
  float a = bf2f((unsigned short)(v & 0xffffu));
  float b = bf2f((unsigned short)(v >> 16));
  float ss = a * a + b * b;
#pragma unroll
  for (int m = 1; m < 64; m <<= 1) ss += __shfl_xor(ss, m, 64);
  float r = rsqrtf(ss * (1.0f / 128.0f) + 1e-6f) * scl;
  *(unsigned*)(base + lane * 2) = ((unsigned)f2bf(b * r) << 16) | (unsigned)f2bf(a * r);
}

// ---------------- flash attention: LDS-staged KV, 2-phase dbuf prefetch -------
// S is computed in base-2 scale (log2e folded into Q); defer-max THR in base-2.
__global__ __launch_bounds__(256, 2)
void attn(const unsigned short* __restrict__ Q, const unsigned short* __restrict__ Kk,
          const unsigned short* __restrict__ Vt, unsigned short* __restrict__ AO) {
  // XCD swizzle: 16 q-blocks of one bh land on one XCD (KV = 1MB fits 4MB L2)
  const int bid = blockIdx.x;
  const int bh = (bid & 7) + 8 * (bid >> 7);   // b*16 + h
  const int qx = (bid >> 3) & 15;
  const int b = bh >> 4, h = bh & 15;
  const int hkv = h >> 2;
  const int t = threadIdx.x;
  const int w = t >> 6, lane = t & 63;
  const int lo = lane & 15, hi = lane >> 4;
  const unsigned short* Qb = Q  + (size_t)bh * 2048 * 128;
  const unsigned short* Kb = Kk + (size_t)(b * 4 + hkv) * 2048 * 128;
  const unsigned short* Vb = Vt + (size_t)(b * 4 + hkv) * 128 * 2048;
  const int q0 = qx * 128 + w * 32;

  __shared__ __align__(16) unsigned short Klds[2][64 * 128];  // 32 KB (swizzled)
  __shared__ __align__(16) unsigned short Vlds[2][128 * 64];  // 32 KB (swizzled)
  __shared__ __align__(16) unsigned short Plds[4][32 * 64];   // 16 KB (wave-private)

  // hoisted per-lane swizzled read offsets (row&7 == lo&7 since rows are 16n+lo)
  const int swz = (lo & 7) << 4;  // byte XOR
  int kcol[4], vcol[2];
#pragma unroll
  for (int kd = 0; kd < 4; ++kd) kcol[kd] = ((kd * 64 + hi * 16) ^ swz) >> 1;
#pragma unroll
  for (int ks = 0; ks < 2; ++ks) vcol[ks] = ((ks * 64 + hi * 16) ^ swz) >> 1;
  unsigned short* Pw = Plds[w];

  bf16x8 qf[2][4];
#pragma unroll
  for (int qm = 0; qm < 2; ++qm)
#pragma unroll
    for (int kd = 0; kd < 4; ++kd)
      qf[qm][kd] = *(const bf16x8*)&Qb[(size_t)(q0 + qm * 16 + lo) * 128 + kd * 32 + hi * 8];

  f32x4 Oa[2][8] = {};
  float mrow[2][4], srow[2][4];
#pragma unroll
  for (int qm = 0; qm < 2; ++qm)
#pragma unroll
    for (int i = 0; i < 4; ++i) { mrow[qm][i] = -1e30f; srow[qm][i] = 0.f; }

  // --- staging helpers (source pre-swizzled, LDS write linear: rule #21) ---
  // K tile: 64 rows x 128 shorts (16 granules/row); V^T tile: 128 rows x 64 shorts (8/row)
#define STAGE_KV(bufi, kt_)                                                      \
  {                                                                              \
    const unsigned short* gK = Kb + (size_t)(kt_) * 128;                         \
    const unsigned short* gV = Vb + (kt_);                                       \
    _Pragma("unroll")                                                            \
    for (int j = 0; j < 4; ++j) {                                                \
      int gi = j * 256 + t;                                                      \
      int kr = gi >> 4, kg = (gi & 15) ^ (kr & 7);                               \
      async16(&Klds[bufi][gi * 8], gK + (size_t)kr * 128 + kg * 8);              \
      int vr = gi >> 3, vg = (gi & 7) ^ (vr & 7);                                \
      async16(&Vlds[bufi][gi * 8], gV + (size_t)vr * 2048 + vg * 8);             \
    }                                                                            \
  }

  STAGE_KV(0, 0);
  __syncthreads();

  int cur = 0;
  for (int kt = 0; kt < 2048; kt += 64) {
    if (kt + 64 < 2048) STAGE_KV(cur ^ 1, kt + 64);

    const unsigned short* KL = Klds[cur];
    const unsigned short* VL = Vlds[cur];

    // ---- QK^T ----
    f32x4 S[2][4] = {};
#pragma unroll
    for (int kn = 0; kn < 4; ++kn) {
      const unsigned short* kr = KL + (kn * 16 + lo) * 128;
      bf16x8 kf[4];
#pragma unroll
      for (int kd = 0; kd < 4; ++kd) kf[kd] = *(const bf16x8*)(kr + kcol[kd]);
#pragma unroll
      for (int qm = 0; qm < 2; ++qm)
#pragma unroll
        for (int kd = 0; kd < 4; ++kd)
          S[qm][kn] = __builtin_amdgcn_mfma_f32_16x16x32_bf16(qf[qm][kd], kf[kd], S[qm][kn], 0, 0, 0);
    }

    // ---- online softmax (base-2), defer-max THR=11 => P bounded by 2^11 ----
#pragma unroll
    for (int qm = 0; qm < 2; ++qm) {
      float mx[4];
      bool need = false;
#pragma unroll
      for (int i = 0; i < 4; ++i) {
        float m3 = fmaxf(fmaxf(S[qm][0][i], S[qm][1][i]), fmaxf(S[qm][2][i], S[qm][3][i]));
#pragma unroll
        for (int d = 1; d < 16; d <<= 1) m3 = fmaxf(m3, __shfl_xor(m3, d, 64));
        mx[i] = m3;
        need |= (m3 > mrow[qm][i] + 11.0f);
      }
      if (__any(need)) {
#pragma unroll
        for (int i = 0; i < 4; ++i) {
          float mnew = fmaxf(mrow[qm][i], mx[i]);
          float al = exp2f(mrow[qm][i] - mnew);
          mrow[qm][i] = mnew;
          srow[qm][i] *= al;
#pragma unroll
          for (int dn = 0; dn < 8; ++dn) Oa[qm][dn][i] *= al;
        }
      }
#pragma unroll
      for (int i = 0; i < 4; ++i) {
        float rs = 0.f;
#pragma unroll
        for (int kn = 0; kn < 4; ++kn) {
          float p = exp2f(S[qm][kn][i] - mrow[qm][i]);
          S[qm][kn][i] = p;
          rs += p;
        }
#pragma unroll
        for (int d = 1; d < 16; d <<= 1) rs += __shfl_xor(rs, d, 64);
        srow[qm][i] += rs;
      }
#pragma unroll
      for (int kn = 0; kn < 4; ++kn)
#pragma unroll
        for (int i = 0; i < 4; ++i)
          Pw[(qm * 16 + hi * 4 + i) * 64 + kn * 16 + lo] = f2bf(S[qm][kn][i]);
    }

    // ---- PV (V^T rows from LDS) ----
#pragma unroll
    for (int ks = 0; ks < 2; ++ks) {
      bf16x8 pf[2];
#pragma unroll
      for (int qm = 0; qm < 2; ++qm)
        pf[qm] = *(const bf16x8*)&Pw[(qm * 16 + lo) * 64 + ks * 32 + hi * 8];
#pragma unroll
      for (int dn = 0; dn < 8; ++dn) {
        bf16x8 vf = *(const bf16x8*)(VL + (dn * 16 + lo) * 64 + vcol[ks]);
#pragma unroll
        for (int qm = 0; qm < 2; ++qm)
          Oa[qm][dn] = __builtin_amdgcn_mfma_f32_16x16x32_bf16(pf[qm], vf, Oa[qm][dn], 0, 0, 0);
      }
    }

    __syncthreads();  // drains prefetch (vmcnt) + all LDS reads before overwrite
    cur ^= 1;
  }

#pragma unroll
  for (int qm = 0; qm < 2; ++qm)
#pragma unroll
    for (int dn = 0; dn < 8; ++dn)
#pragma unroll
      for (int i = 0; i < 4; ++i) {
        int tt = q0 + qm * 16 + hi * 4 + i;
        float o = Oa[qm][dn][i] / srow[qm][i];
        AO[((size_t)(b * 2048 + tt)) * 2048 + h * 128 + dn * 16 + lo] = f2bf(o);
      }
}

// ------------------------------- launcher -------------------------------------
extern "C" void kernel_launch(void* const* d_in, const int* in_sizes, int n_in,
                              void* d_out, int out_size, void* d_ws, size_t ws_size,
                              hipStream_t stream) {
  const float* x_q = (const float*)d_in[0];
  const float* Wq  = (const float*)d_in[1];
  const float* Wk  = (const float*)d_in[2];
  const float* Wv  = (const float*)d_in[3];
  const float* Wo  = (const float*)d_in[4];
  float* out = (float*)d_out;

  char* ws = (char*)d_ws;
  unsigned short* Xb    = (unsigned short*)(ws);             // 16.8 MB (reused as AO)
  unsigned short* WqkvT = (unsigned short*)(ws + 16777216);  // 12.6 MB
  unsigned short* WoT   = (unsigned short*)(ws + 29360128);  //  8.4 MB
  unsigned short* Qn    = (unsigned short*)(ws + 37748736);  // 16.8 MB
  unsigned short* Kn    = (unsigned short*)(ws + 54525952);  //  4.2 MB
  unsigned short* Vt    = (unsigned short*)(ws + 58720256);  //  4.2 MB
  unsigned short* AO    = Xb;

  cast_x<<<2048, 256, 0, stream>>>(x_q, Xb, (4096 * 2048) / 8);
  transpose_cast<<<dim3(2048 / 32, 2048 / 32), dim3(32, 8), 0, stream>>>(Wq, WqkvT, 2048, 2048);
  transpose_cast<<<dim3(512 / 32, 2048 / 32), dim3(32, 8), 0, stream>>>(Wk, WqkvT + 2048 * 2048, 2048, 512);
  transpose_cast<<<dim3(512 / 32, 2048 / 32), dim3(32, 8), 0, stream>>>(Wv, WqkvT + 2560 * 2048, 2048, 512);
  transpose_cast<<<dim3(2048 / 32, 2048 / 32), dim3(32, 8), 0, stream>>>(Wo, WoT, 2048, 2048);

  gemm_bt<1><<<dim3(3072 / 128, 4096 / 128), 256, 0, stream>>>(Xb, WqkvT, 2048, nullptr, 0, Qn, Kn, Vt);
  // Q scale = (1/sqrt(128)) * log2(e)  -> softmax runs in base-2
  qk_norm<<<(65536 + 16384) / 4, 256, 0, stream>>>(Qn, Kn, 0.12751742f);
  attn<<<512, 256, 0, stream>>>(Qn, Kn, Vt, AO);
  gemm_bt<0><<<dim3(2048 / 128, 4096 / 128), 256, 0, stream>>>(AO, WoT, 2048, out, 2048,
                                                               nullptr, nullptr, nullptr);
}

// Round 4
// 243.322 us; speedup vs baseline: 2.3321x; 1.2197x over previous
//
#include <hip/hip_runtime.h>

typedef __attribute__((ext_vector_type(4))) float f32x4;
typedef __attribute__((ext_vector_type(16))) float f32x16;
typedef __attribute__((ext_vector_type(8))) short bf16x8;
typedef __attribute__((ext_vector_type(4))) unsigned u32x4;

#define DEV __device__ __forceinline__

DEV unsigned short f2bf(float f) {            // RTNE f32 -> bf16
  unsigned u = __float_as_uint(f);
  unsigned r = (u + 0x7FFFu + ((u >> 16) & 1u)) >> 16;
  return (unsigned short)r;
}
DEV float bf2f(unsigned short h) { return __uint_as_float(((unsigned)h) << 16); }

DEV unsigned pkbf(float lo, float hi) {       // 2x f32 -> packed bf16x2 (RTNE)
  return ((unsigned)f2bf(hi) << 16) | (unsigned)f2bf(lo);
}
DEV bf16x8 frag4(unsigned a, unsigned b, unsigned c, unsigned d) {
  u32x4 u = {a, b, c, d};
  return __builtin_bit_cast(bf16x8, u);
}

typedef __attribute__((address_space(1))) void gas_t;
typedef __attribute__((address_space(3))) void las_t;
DEV void async16(void* lds, const void* g) {
  __builtin_amdgcn_global_load_lds((gas_t*)g, (las_t*)lds, 16, 0, 0);
}

// ---------------- elementwise cast: f32 -> bf16, 8 elems/thread ----------------
__global__ void cast_x(const float* __restrict__ x, unsigned short* __restrict__ y, int n8) {
  int idx = blockIdx.x * blockDim.x + threadIdx.x;
  int stride = gridDim.x * blockDim.x;
  for (; idx < n8; idx += stride) {
    const float4* p = (const float4*)(x + (size_t)idx * 8);
    float4 v0 = p[0], v1 = p[1];
    bf16x8 o;
    o[0] = (short)f2bf(v0.x); o[1] = (short)f2bf(v0.y);
    o[2] = (short)f2bf(v0.z); o[3] = (short)f2bf(v0.w);
    o[4] = (short)f2bf(v1.x); o[5] = (short)f2bf(v1.y);
    o[6] = (short)f2bf(v1.z); o[7] = (short)f2bf(v1.w);
    *(bf16x8*)(y + (size_t)idx * 8) = o;
  }
}

// ---------------- transpose + cast: W[K][N] f32 -> Wt[N][K] bf16 ----------------
__global__ void transpose_cast(const float* __restrict__ W, unsigned short* __restrict__ Wt,
                               int Kdim, int Nw) {
  __shared__ float tile[32][33];
  int n0 = blockIdx.x * 32, k0 = blockIdx.y * 32;
  int tx = threadIdx.x, ty = threadIdx.y;
#pragma unroll
  for (int r = ty; r < 32; r += 8)
    tile[r][tx] = W[(size_t)(k0 + r) * Nw + n0 + tx];
  __syncthreads();
#pragma unroll
  for (int r = ty; r < 32; r += 8)
    Wt[(size_t)(n0 + r) * Kdim + k0 + tx] = f2bf(tile[tx][r]);
}

// ---------------- GEMM (m97 structure): A[M][K] x Bt[N][K] -------------------
template <int EPI>
__global__ __launch_bounds__(256, 2)
void gemm_bt(const unsigned short* __restrict__ A, const unsigned short* __restrict__ Bt,
             int Kr, float* __restrict__ Cf, int Nr,
             unsigned short* __restrict__ Qn, unsigned short* __restrict__ Kn,
             unsigned short* __restrict__ Vt) {
  __shared__ __align__(16) unsigned short lsA[128 * 32];
  __shared__ __align__(16) unsigned short lsB[128 * 32];
  const int t = threadIdx.x;
  const int lane = t & 63;
  const int w = t >> 6, wr = w >> 1, wc = w & 1;
  const int lo = lane & 15, hi = lane >> 4;
  const int m0 = blockIdx.y * 128, n0 = blockIdx.x * 128;

  const int c0 = t, c1 = t + 256;
  const unsigned short* gA0 = A + (size_t)(m0 + (c0 >> 2)) * Kr + (c0 & 3) * 8;
  const unsigned short* gA1 = A + (size_t)(m0 + (c1 >> 2)) * Kr + (c1 & 3) * 8;
  const unsigned short* gB0 = Bt + (size_t)(n0 + (c0 >> 2)) * Kr + (c0 & 3) * 8;
  const unsigned short* gB1 = Bt + (size_t)(n0 + (c1 >> 2)) * Kr + (c1 & 3) * 8;
  unsigned short* lA0 = lsA + c0 * 8;
  unsigned short* lA1 = lsA + c1 * 8;
  unsigned short* lB0 = lsB + c0 * 8;
  unsigned short* lB1 = lsB + c1 * 8;

  f32x4 acc[4][4] = {};

  for (int kt = 0; kt < Kr; kt += 32) {
    async16(lA0, gA0 + kt);
    async16(lA1, gA1 + kt);
    async16(lB0, gB0 + kt);
    async16(lB1, gB1 + kt);
    __syncthreads();
    bf16x8 af[4], bfr[4];
#pragma unroll
    for (int i = 0; i < 4; ++i) {
      af[i]  = *(const bf16x8*)&lsA[(wr * 64 + i * 16 + lo) * 32 + hi * 8];
      bfr[i] = *(const bf16x8*)&lsB[(wc * 64 + i * 16 + lo) * 32 + hi * 8];
    }
#pragma unroll
    for (int mi = 0; mi < 4; ++mi)
#pragma unroll
      for (int ni = 0; ni < 4; ++ni)
        acc[mi][ni] = __builtin_amdgcn_mfma_f32_16x16x32_bf16(af[mi], bfr[ni], acc[mi][ni], 0, 0, 0);
    __syncthreads();
  }

#pragma unroll
  for (int mi = 0; mi < 4; ++mi)
#pragma unroll
    for (int ni = 0; ni < 4; ++ni)
#pragma unroll
      for (int i = 0; i < 4; ++i) {
        int gm = m0 + wr * 64 + mi * 16 + hi * 4 + i;
        int gn = n0 + wc * 64 + ni * 16 + lo;
        float v = acc[mi][ni][i];
        if (EPI == 0) {
          Cf[(size_t)gm * Nr + gn] = v;
        } else {
          unsigned short bv = f2bf(v);
          int bb = gm >> 11, tt = gm & 2047;
          if (gn < 2048) {                      // Q: [b][h][t][d]
            int hh = gn >> 7, dd = gn & 127;
            Qn[(((size_t)bb * 16 + hh) * 2048 + tt) * 128 + dd] = bv;
          } else if (gn < 2560) {               // K: [b][hkv][t][d]
            int g2 = gn - 2048, hh = g2 >> 7, dd = g2 & 127;
            Kn[(((size_t)bb * 4 + hh) * 2048 + tt) * 128 + dd] = bv;
          } else {                              // V^T: [b][hkv][d][t]
            int g2 = gn - 2560, hh = g2 >> 7, dd = g2 & 127;
            Vt[(((size_t)bb * 4 + hh) * 128 + dd) * 2048 + tt] = bv;
          }
        }
      }
}

// ---------------- QK RMS-norm (in place); Q also gets (1/sqrt(D))*log2(e) ------
__global__ __launch_bounds__(256)
void qk_norm(unsigned short* __restrict__ Qn, unsigned short* __restrict__ Kn, float qscale) {
  int row = blockIdx.x * 4 + (threadIdx.x >> 6);
  int lane = threadIdx.x & 63;
  unsigned short* base;
  float scl;
  if (row < 65536) { base = Qn + (size_t)row * 128; scl = qscale; }
  else             { base = Kn + (size_t)(row - 65536) * 128; scl = 1.0f; }
  unsigned v = *(const unsigned*)(base + lane * 2);
  float a = bf2f((unsigned short)(v & 0xffffu));
  float b = bf2f((unsigned short)(v >> 16));
  float ss = a * a + b * b;
#pragma unroll
  for (int m = 1; m < 64; m <<= 1) ss += __shfl_xor(ss, m, 64);
  float r = rsqrtf(ss * (1.0f / 128.0f) + 1e-6f) * scl;
  *(unsigned*)(base + lane * 2) = ((unsigned)f2bf(b * r) << 16) | (unsigned)f2bf(a * r);
}

// ---------------- flash attention: swapped-QK^T 32x32 MFMA, in-register softmax
// Each wave owns 32 q-rows (q = lane&31); lane holds full P slices in regs.
// S in base-2 (log2e folded into Q). No P LDS round-trip.
__global__ __launch_bounds__(256, 2)
void attn(const unsigned short* __restrict__ Q, const unsigned short* __restrict__ Kk,
          const unsigned short* __restrict__ Vt, unsigned short* __restrict__ AO) {
  const int bid = blockIdx.x;
  const int bh = (bid & 7) + 8 * (bid >> 7);   // XCD swizzle (512 % 8 == 0, bijective)
  const int qx = (bid >> 3) & 15;
  const int b = bh >> 4, h = bh & 15;
  const int hkv = h >> 2;
  const int t = threadIdx.x;
  const int w = t >> 6, lane = t & 63;
  const int qi = lane & 31, h1 = lane >> 5;
  const unsigned short* Qb = Q  + (size_t)bh * 2048 * 128;
  const unsigned short* Kb = Kk + (size_t)(b * 4 + hkv) * 2048 * 128;
  const unsigned short* Vb = Vt + (size_t)(b * 4 + hkv) * 128 * 2048;
  const int q0 = qx * 128 + w * 32;

  __shared__ __align__(16) unsigned short Klds[2][64 * 128];  // 32 KB, granule^(row&15)
  __shared__ __align__(16) unsigned short Vlds[2][128 * 64];  // 32 KB, granule^(row&7)

  // Q as B-operand fragments: qf[s] = Q[q0+qi][16s + h1*8 .. +8]
  bf16x8 qf[8];
#pragma unroll
  for (int s = 0; s < 8; ++s)
    qf[s] = *(const bf16x8*)&Qb[(size_t)(q0 + qi) * 128 + s * 16 + h1 * 8];

  f32x16 Oc[4] = {};            // O^T acc: col=q (lane), row=d-offset
  float mrow = -1e30f, srow = 0.f;

  // staging: pre-swizzled global source, linear LDS dest (rule #21)
#define STAGE_KV(bufi, kt_)                                                      \
  {                                                                              \
    const unsigned short* gK = Kb + (size_t)(kt_) * 128;                         \
    const unsigned short* gV = Vb + (kt_);                                       \
    _Pragma("unroll")                                                            \
    for (int j = 0; j < 4; ++j) {                                                \
      int gi = j * 256 + t;                                                      \
      int kr = gi >> 4, kg = (gi & 15) ^ (kr & 15);                              \
      async16(&Klds[bufi][gi * 8], gK + (size_t)kr * 128 + kg * 8);              \
      int vr = gi >> 3, vg = (gi & 7) ^ (vr & 7);                                \
      async16(&Vlds[bufi][gi * 8], gV + (size_t)vr * 2048 + vg * 8);             \
    }                                                                            \
  }

  STAGE_KV(0, 0);
  __syncthreads();

  int cur = 0;
  for (int kt = 0; kt < 2048; kt += 64) {
    if (kt + 64 < 2048) STAGE_KV(cur ^ 1, kt + 64);

    const unsigned short* KL = Klds[cur];
    const unsigned short* VL = Vlds[cur];

    // ---- QK^T (swapped): S[mt] = K_tile^T-frag x Q-frag; lane q = qi ----
    f32x16 S[2] = {};
#pragma unroll
    for (int mt = 0; mt < 2; ++mt) {
      const int krow = mt * 32 + qi;
      const unsigned short* krp = KL + krow * 128;
      const int rswz = krow & 15;
#pragma unroll
      for (int s = 0; s < 8; ++s) {
        bf16x8 kf = *(const bf16x8*)(krp + (((2 * s + h1) ^ rswz) << 3));
        S[mt] = __builtin_amdgcn_mfma_f32_32x32x16_bf16(kf, qf[s], S[mt], 0, 0, 0);
      }
    }
    // lane now holds P[q=qi][key = mt*32 + (r&3) + 8*(r>>2) + 4*h1], r=0..15

    // ---- in-register online softmax (base-2), defer-max THR=8 ----
    float mx = S[0][0];
#pragma unroll
    for (int r = 1; r < 16; ++r) mx = fmaxf(mx, S[0][r]);
#pragma unroll
    for (int r = 0; r < 16; ++r) mx = fmaxf(mx, S[1][r]);
    mx = fmaxf(mx, __shfl_xor(mx, 32, 64));
    if (__any(mx > mrow + 8.0f)) {
      float mnew = fmaxf(mrow, mx);
      float al = __builtin_amdgcn_exp2f(mrow - mnew);
      mrow = mnew;
      srow *= al;
#pragma unroll
      for (int dt = 0; dt < 4; ++dt)
#pragma unroll
        for (int r = 0; r < 16; ++r) Oc[dt][r] *= al;
    }
    float rs = 0.f;
#pragma unroll
    for (int mt = 0; mt < 2; ++mt)
#pragma unroll
      for (int r = 0; r < 16; ++r) {
        float p = __builtin_amdgcn_exp2f(S[mt][r] - mrow);
        S[mt][r] = p;
        rs += p;
      }
    rs += __shfl_xor(rs, 32, 64);
    srow += rs;

    // ---- P -> bf16, cross-half exchange, PV (O^T = V^T-frag x P-frag) ----
#pragma unroll
    for (int mt = 0; mt < 2; ++mt) {
      unsigned wd[8];
#pragma unroll
      for (int i2 = 0; i2 < 8; ++i2) wd[i2] = pkbf(S[mt][2 * i2], S[mt][2 * i2 + 1]);
      unsigned r0 = __shfl_xor(h1 ? wd[0] : wd[2], 32, 64);
      unsigned r1 = __shfl_xor(h1 ? wd[1] : wd[3], 32, 64);
      unsigned r2 = __shfl_xor(h1 ? wd[4] : wd[6], 32, 64);
      unsigned r3 = __shfl_xor(h1 ? wd[5] : wd[7], 32, 64);
      bf16x8 pf0 = frag4(h1 ? r0 : wd[0], h1 ? r1 : wd[1], h1 ? wd[2] : r0, h1 ? wd[3] : r1);
      bf16x8 pf1 = frag4(h1 ? r2 : wd[4], h1 ? r3 : wd[5], h1 ? wd[6] : r2, h1 ? wd[7] : r3);
#pragma unroll
      for (int dt = 0; dt < 4; ++dt) {
        const int vrow = dt * 32 + qi;
        const unsigned short* vrp = VL + vrow * 64;
        const int vswz = vrow & 7;
        bf16x8 v0 = *(const bf16x8*)(vrp + (((mt * 4 + 0 + h1) ^ vswz) << 3));
        bf16x8 v1 = *(const bf16x8*)(vrp + (((mt * 4 + 2 + h1) ^ vswz) << 3));
        Oc[dt] = __builtin_amdgcn_mfma_f32_32x32x16_bf16(v0, pf0, Oc[dt], 0, 0, 0);
        Oc[dt] = __builtin_amdgcn_mfma_f32_32x32x16_bf16(v1, pf1, Oc[dt], 0, 0, 0);
      }
    }

    __syncthreads();  // prefetch landed + all LDS reads done before overwrite
    cur ^= 1;
  }

  // ---- epilogue: O = Oc / srow; lane writes 32 d-values for its q row ----
  const float inv = 1.0f / srow;
  const size_t orow = ((size_t)(b * 2048 + q0 + qi)) * 2048 + h * 128;
#pragma unroll
  for (int dt = 0; dt < 4; ++dt)
#pragma unroll
    for (int rq = 0; rq < 4; ++rq) {
      int d0 = dt * 32 + 8 * rq + 4 * h1;
      float v0 = Oc[dt][4 * rq + 0] * inv, v1 = Oc[dt][4 * rq + 1] * inv;
      float v2 = Oc[dt][4 * rq + 2] * inv, v3 = Oc[dt][4 * rq + 3] * inv;
      unsigned u0 = (unsigned)f2bf(v0) | ((unsigned)f2bf(v1) << 16);
      unsigned u1 = (unsigned)f2bf(v2) | ((unsigned)f2bf(v3) << 16);
      uint2 st = {u0, u1};
      *(uint2*)((unsigned short*)AO + orow + d0) = st;
    }
}

// ------------------------------- launcher -------------------------------------
extern "C" void kernel_launch(void* const* d_in, const int* in_sizes, int n_in,
                              void* d_out, int out_size, void* d_ws, size_t ws_size,
                              hipStream_t stream) {
  const float* x_q = (const float*)d_in[0];
  const float* Wq  = (const float*)d_in[1];
  const float* Wk  = (const float*)d_in[2];
  const float* Wv  = (const float*)d_in[3];
  const float* Wo  = (const float*)d_in[4];
  float* out = (float*)d_out;

  char* ws = (char*)d_ws;
  unsigned short* Xb    = (unsigned short*)(ws);             // 16.8 MB (reused as AO)
  unsigned short* WqkvT = (unsigned short*)(ws + 16777216);  // 12.6 MB
  unsigned short* WoT   = (unsigned short*)(ws + 29360128);  //  8.4 MB
  unsigned short* Qn    = (unsigned short*)(ws + 37748736);  // 16.8 MB
  unsigned short* Kn    = (unsigned short*)(ws + 54525952);  //  4.2 MB
  unsigned short* Vt    = (unsigned short*)(ws + 58720256);  //  4.2 MB
  unsigned short* AO    = Xb;

  cast_x<<<2048, 256, 0, stream>>>(x_q, Xb, (4096 * 2048) / 8);
  transpose_cast<<<dim3(2048 / 32, 2048 / 32), dim3(32, 8), 0, stream>>>(Wq, WqkvT, 2048, 2048);
  transpose_cast<<<dim3(512 / 32, 2048 / 32), dim3(32, 8), 0, stream>>>(Wk, WqkvT + 2048 * 2048, 2048, 512);
  transpose_cast<<<dim3(512 / 32, 2048 / 32), dim3(32, 8), 0, stream>>>(Wv, WqkvT + 2560 * 2048, 2048, 512);
  transpose_cast<<<dim3(2048 / 32, 2048 / 32), dim3(32, 8), 0, stream>>>(Wo, WoT, 2048, 2048);

  gemm_bt<1><<<dim3(3072 / 128, 4096 / 128), 256, 0, stream>>>(Xb, WqkvT, 2048, nullptr, 0, Qn, Kn, Vt);
  // Q scale = (1/sqrt(128)) * log2(e)  -> softmax runs in base-2
  qk_norm<<<(65536 + 16384) / 4, 256, 0, stream>>>(Qn, Kn, 0.12751742f);
  attn<<<512, 256, 0, stream>>>(Qn, Kn, Vt, AO);
  gemm_bt<0><<<dim3(2048 / 128, 4096 / 128), 256, 0, stream>>>(AO, WoT, 2048, out, 2048,
                                                               nullptr, nullptr, nullptr);
}

// Round 5
// 240.433 us; speedup vs baseline: 2.3601x; 1.0120x over previous
//
#include <hip/hip_runtime.h>

typedef __attribute__((ext_vector_type(4))) float f32x4;
typedef __attribute__((ext_vector_type(16))) float f32x16;
typedef __attribute__((ext_vector_type(8))) short bf16x8;
typedef __attribute__((ext_vector_type(4))) unsigned u32x4;

#define DEV __device__ __forceinline__

DEV unsigned short f2bf(float f) {            // RTNE f32 -> bf16
  unsigned u = __float_as_uint(f);
  unsigned r = (u + 0x7FFFu + ((u >> 16) & 1u)) >> 16;
  return (unsigned short)r;
}
DEV float bf2f(unsigned short h) { return __uint_as_float(((unsigned)h) << 16); }

DEV unsigned cvtpk(float lo, float hi) {      // packed f32x2 -> bf16x2 (HW RTNE)
  unsigned r;
  asm("v_cvt_pk_bf16_f32 %0, %1, %2" : "=v"(r) : "v"(lo), "v"(hi));
  return r;
}
DEV bf16x8 frag4(unsigned a, unsigned b, unsigned c, unsigned d) {
  u32x4 u = {a, b, c, d};
  return __builtin_bit_cast(bf16x8, u);
}

typedef __attribute__((address_space(1))) void gas_t;
typedef __attribute__((address_space(3))) void las_t;
DEV void async16(void* lds, const void* g) {
  __builtin_amdgcn_global_load_lds((gas_t*)g, (las_t*)lds, 16, 0, 0);
}

// ---------------- elementwise cast: f32 -> bf16, 8 elems/thread ----------------
__global__ void cast_x(const float* __restrict__ x, unsigned short* __restrict__ y, int n8) {
  int idx = blockIdx.x * blockDim.x + threadIdx.x;
  int stride = gridDim.x * blockDim.x;
  for (; idx < n8; idx += stride) {
    const float4* p = (const float4*)(x + (size_t)idx * 8);
    float4 v0 = p[0], v1 = p[1];
    bf16x8 o;
    o[0] = (short)f2bf(v0.x); o[1] = (short)f2bf(v0.y);
    o[2] = (short)f2bf(v0.z); o[3] = (short)f2bf(v0.w);
    o[4] = (short)f2bf(v1.x); o[5] = (short)f2bf(v1.y);
    o[6] = (short)f2bf(v1.z); o[7] = (short)f2bf(v1.w);
    *(bf16x8*)(y + (size_t)idx * 8) = o;
  }
}

// ---------------- transpose + cast: W[K][N] f32 -> Wt[N][K] bf16 ----------------
__global__ void transpose_cast(const float* __restrict__ W, unsigned short* __restrict__ Wt,
                               int Kdim, int Nw) {
  __shared__ float tile[32][33];
  int n0 = blockIdx.x * 32, k0 = blockIdx.y * 32;
  int tx = threadIdx.x, ty = threadIdx.y;
#pragma unroll
  for (int r = ty; r < 32; r += 8)
    tile[r][tx] = W[(size_t)(k0 + r) * Nw + n0 + tx];
  __syncthreads();
#pragma unroll
  for (int r = ty; r < 32; r += 8)
    Wt[(size_t)(n0 + r) * Kdim + k0 + tx] = f2bf(tile[tx][r]);
}

// ---------------- GEMM (m97 structure): A[M][K] x Bt[N][K] -------------------
template <int EPI>
__global__ __launch_bounds__(256, 2)
void gemm_bt(const unsigned short* __restrict__ A, const unsigned short* __restrict__ Bt,
             int Kr, float* __restrict__ Cf, int Nr,
             unsigned short* __restrict__ Qn, unsigned short* __restrict__ Kn,
             unsigned short* __restrict__ Vt) {
  __shared__ __align__(16) unsigned short lsA[128 * 32];
  __shared__ __align__(16) unsigned short lsB[128 * 32];
  const int t = threadIdx.x;
  const int lane = t & 63;
  const int w = t >> 6, wr = w >> 1, wc = w & 1;
  const int lo = lane & 15, hi = lane >> 4;
  const int m0 = blockIdx.y * 128, n0 = blockIdx.x * 128;

  const int c0 = t, c1 = t + 256;
  const unsigned short* gA0 = A + (size_t)(m0 + (c0 >> 2)) * Kr + (c0 & 3) * 8;
  const unsigned short* gA1 = A + (size_t)(m0 + (c1 >> 2)) * Kr + (c1 & 3) * 8;
  const unsigned short* gB0 = Bt + (size_t)(n0 + (c0 >> 2)) * Kr + (c0 & 3) * 8;
  const unsigned short* gB1 = Bt + (size_t)(n0 + (c1 >> 2)) * Kr + (c1 & 3) * 8;
  unsigned short* lA0 = lsA + c0 * 8;
  unsigned short* lA1 = lsA + c1 * 8;
  unsigned short* lB0 = lsB + c0 * 8;
  unsigned short* lB1 = lsB + c1 * 8;

  f32x4 acc[4][4] = {};

  for (int kt = 0; kt < Kr; kt += 32) {
    async16(lA0, gA0 + kt);
    async16(lA1, gA1 + kt);
    async16(lB0, gB0 + kt);
    async16(lB1, gB1 + kt);
    __syncthreads();
    bf16x8 af[4], bfr[4];
#pragma unroll
    for (int i = 0; i < 4; ++i) {
      af[i]  = *(const bf16x8*)&lsA[(wr * 64 + i * 16 + lo) * 32 + hi * 8];
      bfr[i] = *(const bf16x8*)&lsB[(wc * 64 + i * 16 + lo) * 32 + hi * 8];
    }
#pragma unroll
    for (int mi = 0; mi < 4; ++mi)
#pragma unroll
      for (int ni = 0; ni < 4; ++ni)
        acc[mi][ni] = __builtin_amdgcn_mfma_f32_16x16x32_bf16(af[mi], bfr[ni], acc[mi][ni], 0, 0, 0);
    __syncthreads();
  }

#pragma unroll
  for (int mi = 0; mi < 4; ++mi)
#pragma unroll
    for (int ni = 0; ni < 4; ++ni)
#pragma unroll
      for (int i = 0; i < 4; ++i) {
        int gm = m0 + wr * 64 + mi * 16 + hi * 4 + i;
        int gn = n0 + wc * 64 + ni * 16 + lo;
        float v = acc[mi][ni][i];
        if (EPI == 0) {
          Cf[(size_t)gm * Nr + gn] = v;
        } else {
          unsigned short bv = f2bf(v);
          int bb = gm >> 11, tt = gm & 2047;
          if (gn < 2048) {                      // Q: [b][h][t][d]
            int hh = gn >> 7, dd = gn & 127;
            Qn[(((size_t)bb * 16 + hh) * 2048 + tt) * 128 + dd] = bv;
          } else if (gn < 2560) {               // K: [b][hkv][t][d]
            int g2 = gn - 2048, hh = g2 >> 7, dd = g2 & 127;
            Kn[(((size_t)bb * 4 + hh) * 2048 + tt) * 128 + dd] = bv;
          } else {                              // V^T: [b][hkv][d][t]
            int g2 = gn - 2560, hh = g2 >> 7, dd = g2 & 127;
            Vt[(((size_t)bb * 4 + hh) * 128 + dd) * 2048 + tt] = bv;
          }
        }
      }
}

// ---------------- QK RMS-norm (in place); Q also gets (1/sqrt(D))*log2(e) ------
__global__ __launch_bounds__(256)
void qk_norm(unsigned short* __restrict__ Qn, unsigned short* __restrict__ Kn, float qscale) {
  int row = blockIdx.x * 4 + (threadIdx.x >> 6);
  int lane = threadIdx.x & 63;
  unsigned short* base;
  float scl;
  if (row < 65536) { base = Qn + (size_t)row * 128; scl = qscale; }
  else             { base = Kn + (size_t)(row - 65536) * 128; scl = 1.0f; }
  unsigned v = *(const unsigned*)(base + lane * 2);
  float a = bf2f((unsigned short)(v & 0xffffu));
  float b = bf2f((unsigned short)(v >> 16));
  float ss = a * a + b * b;
#pragma unroll
  for (int m = 1; m < 64; m <<= 1) ss += __shfl_xor(ss, m, 64);
  float r = rsqrtf(ss * (1.0f / 128.0f) + 1e-6f) * scl;
  *(unsigned*)(base + lane * 2) = ((unsigned)f2bf(b * r) << 16) | (unsigned)f2bf(a * r);
}

// ---------------- flash attention: swapped-QK^T 32x32 MFMA, in-register softmax
__global__ __launch_bounds__(256, 2)
void attn(const unsigned short* __restrict__ Q, const unsigned short* __restrict__ Kk,
          const unsigned short* __restrict__ Vt, unsigned short* __restrict__ AO) {
  const int bid = blockIdx.x;
  const int bh = (bid & 7) + 8 * (bid >> 7);   // XCD swizzle (512 % 8 == 0, bijective)
  const int qx = (bid >> 3) & 15;
  const int b = bh >> 4, h = bh & 15;
  const int hkv = h >> 2;
  const int t = threadIdx.x;
  const int w = t >> 6, lane = t & 63;
  const int qi = lane & 31, h1 = lane >> 5;
  const unsigned short* Qb = Q  + (size_t)bh * 2048 * 128;
  const unsigned short* Kb = Kk + (size_t)(b * 4 + hkv) * 2048 * 128;
  const unsigned short* Vb = Vt + (size_t)(b * 4 + hkv) * 128 * 2048;
  const int q0 = qx * 128 + w * 32;

  __shared__ __align__(16) unsigned short Klds[2][64 * 128];  // 32 KB, granule^(row&15)
  __shared__ __align__(16) unsigned short Vlds[2][128 * 64];  // 32 KB, granule^(row&7)

  // Q as B-operand fragments: qf[s] = Q[q0+qi][16s + h1*8 .. +8]
  bf16x8 qf[8];
#pragma unroll
  for (int s = 0; s < 8; ++s)
    qf[s] = *(const bf16x8*)&Qb[(size_t)(q0 + qi) * 128 + s * 16 + h1 * 8];

  f32x16 Oc[4] = {};            // O^T acc: col=q (lane), row=d-offset
  float mrow = -1e30f, srow = 0.f;

  // staging: pre-swizzled global source, linear LDS dest (rule #21)
#define STAGE_KV(bufi, kt_)                                                      \
  {                                                                              \
    const unsigned short* gK = Kb + (size_t)(kt_) * 128;                         \
    const unsigned short* gV = Vb + (kt_);                                       \
    _Pragma("unroll")                                                            \
    for (int j = 0; j < 4; ++j) {                                                \
      int gi = j * 256 + t;                                                      \
      int kr = gi >> 4, kg = (gi & 15) ^ (kr & 15);                              \
      async16(&Klds[bufi][gi * 8], gK + (size_t)kr * 128 + kg * 8);              \
      int vr = gi >> 3, vg = (gi & 7) ^ (vr & 7);                                \
      async16(&Vlds[bufi][gi * 8], gV + (size_t)vr * 2048 + vg * 8);             \
    }                                                                            \
  }

  STAGE_KV(0, 0);
  __syncthreads();

  int cur = 0;
  for (int kt = 0; kt < 2048; kt += 64) {
    if (kt + 64 < 2048) STAGE_KV(cur ^ 1, kt + 64);

    const unsigned short* KL = Klds[cur];
    const unsigned short* VL = Vlds[cur];

    // ---- QK^T (swapped): S[mt] = K_tile^T-frag x Q-frag; lane q = qi ----
    f32x16 S[2] = {};
    __builtin_amdgcn_s_setprio(1);
#pragma unroll
    for (int mt = 0; mt < 2; ++mt) {
      const int krow = mt * 32 + qi;
      const unsigned short* krp = KL + krow * 128;
      const int rswz = krow & 15;
#pragma unroll
      for (int s = 0; s < 8; ++s) {
        bf16x8 kf = *(const bf16x8*)(krp + (((2 * s + h1) ^ rswz) << 3));
        S[mt] = __builtin_amdgcn_mfma_f32_32x32x16_bf16(kf, qf[s], S[mt], 0, 0, 0);
      }
    }
    __builtin_amdgcn_s_setprio(0);
    // lane holds P[q=qi][key = mt*32 + (r&3) + 8*(r>>2) + 4*h1], r=0..15

    // ---- in-register online softmax (base-2), tree reductions ----
    float t8[8];
#pragma unroll
    for (int r = 0; r < 8; ++r)
      t8[r] = fmaxf(fmaxf(S[0][r], S[0][r + 8]), fmaxf(S[1][r], S[1][r + 8]));
#pragma unroll
    for (int r = 0; r < 4; ++r) t8[r] = fmaxf(t8[r], t8[r + 4]);
    float mx = fmaxf(fmaxf(t8[0], t8[1]), fmaxf(t8[2], t8[3]));
    mx = fmaxf(mx, __shfl_xor(mx, 32, 64));
    if (__any(mx > mrow + 8.0f)) {             // defer-max THR=8 (base-2)
      float mnew = fmaxf(mrow, mx);
      float al = __builtin_amdgcn_exp2f(mrow - mnew);
      mrow = mnew;
      srow *= al;
#pragma unroll
      for (int dt = 0; dt < 4; ++dt)
#pragma unroll
        for (int r = 0; r < 16; ++r) Oc[dt][r] *= al;
    }
#pragma unroll
    for (int mt = 0; mt < 2; ++mt)
#pragma unroll
      for (int r = 0; r < 16; ++r)
        S[mt][r] = __builtin_amdgcn_exp2f(S[mt][r] - mrow);
    float s8[8];
#pragma unroll
    for (int r = 0; r < 8; ++r)
      s8[r] = (S[0][r] + S[0][r + 8]) + (S[1][r] + S[1][r + 8]);
#pragma unroll
    for (int r = 0; r < 4; ++r) s8[r] += s8[r + 4];
    float rs = (s8[0] + s8[1]) + (s8[2] + s8[3]);
    rs += __shfl_xor(rs, 32, 64);
    srow += rs;

    // ---- P -> bf16 (HW cvt_pk), cross-half exchange, PV ----
    __builtin_amdgcn_s_setprio(1);
#pragma unroll
    for (int mt = 0; mt < 2; ++mt) {
      unsigned wd[8];
#pragma unroll
      for (int i2 = 0; i2 < 8; ++i2) wd[i2] = cvtpk(S[mt][2 * i2], S[mt][2 * i2 + 1]);
      unsigned r0 = __shfl_xor(h1 ? wd[0] : wd[2], 32, 64);
      unsigned r1 = __shfl_xor(h1 ? wd[1] : wd[3], 32, 64);
      unsigned r2 = __shfl_xor(h1 ? wd[4] : wd[6], 32, 64);
      unsigned r3 = __shfl_xor(h1 ? wd[5] : wd[7], 32, 64);
      bf16x8 pf0 = frag4(h1 ? r0 : wd[0], h1 ? r1 : wd[1], h1 ? wd[2] : r0, h1 ? wd[3] : r1);
      bf16x8 pf1 = frag4(h1 ? r2 : wd[4], h1 ? r3 : wd[5], h1 ? wd[6] : r2, h1 ? wd[7] : r3);
#pragma unroll
      for (int dt = 0; dt < 4; ++dt) {
        const int vrow = dt * 32 + qi;
        const unsigned short* vrp = VL + vrow * 64;
        const int vswz = vrow & 7;
        bf16x8 v0 = *(const bf16x8*)(vrp + (((mt * 4 + 0 + h1) ^ vswz) << 3));
        bf16x8 v1 = *(const bf16x8*)(vrp + (((mt * 4 + 2 + h1) ^ vswz) << 3));
        Oc[dt] = __builtin_amdgcn_mfma_f32_32x32x16_bf16(v0, pf0, Oc[dt], 0, 0, 0);
        Oc[dt] = __builtin_amdgcn_mfma_f32_32x32x16_bf16(v1, pf1, Oc[dt], 0, 0, 0);
      }
    }
    __builtin_amdgcn_s_setprio(0);

    __syncthreads();  // prefetch landed + all LDS reads done before overwrite
    cur ^= 1;
  }

  // ---- epilogue: O = Oc / srow; lane writes 32 d-values for its q row ----
  const float inv = 1.0f / srow;
  const size_t orow = ((size_t)(b * 2048 + q0 + qi)) * 2048 + h * 128;
#pragma unroll
  for (int dt = 0; dt < 4; ++dt)
#pragma unroll
    for (int rq = 0; rq < 4; ++rq) {
      int d0 = dt * 32 + 8 * rq + 4 * h1;
      unsigned u0 = cvtpk(Oc[dt][4 * rq + 0] * inv, Oc[dt][4 * rq + 1] * inv);
      unsigned u1 = cvtpk(Oc[dt][4 * rq + 2] * inv, Oc[dt][4 * rq + 3] * inv);
      uint2 st = {u0, u1};
      *(uint2*)((unsigned short*)AO + orow + d0) = st;
    }
}

// ------------------------------- launcher -------------------------------------
extern "C" void kernel_launch(void* const* d_in, const int* in_sizes, int n_in,
                              void* d_out, int out_size, void* d_ws, size_t ws_size,
                              hipStream_t stream) {
  const float* x_q = (const float*)d_in[0];
  const float* Wq  = (const float*)d_in[1];
  const float* Wk  = (const float*)d_in[2];
  const float* Wv  = (const float*)d_in[3];
  const float* Wo  = (const float*)d_in[4];
  float* out = (float*)d_out;

  char* ws = (char*)d_ws;
  unsigned short* Xb    = (unsigned short*)(ws);             // 16.8 MB (reused as AO)
  unsigned short* WqkvT = (unsigned short*)(ws + 16777216);  // 12.6 MB
  unsigned short* WoT   = (unsigned short*)(ws + 29360128);  //  8.4 MB
  unsigned short* Qn    = (unsigned short*)(ws + 37748736);  // 16.8 MB
  unsigned short* Kn    = (unsigned short*)(ws + 54525952);  //  4.2 MB
  unsigned short* Vt    = (unsigned short*)(ws + 58720256);  //  4.2 MB
  unsigned short* AO    = Xb;

  cast_x<<<2048, 256, 0, stream>>>(x_q, Xb, (4096 * 2048) / 8);
  transpose_cast<<<dim3(2048 / 32, 2048 / 32), dim3(32, 8), 0, stream>>>(Wq, WqkvT, 2048, 2048);
  transpose_cast<<<dim3(512 / 32, 2048 / 32), dim3(32, 8), 0, stream>>>(Wk, WqkvT + 2048 * 2048, 2048, 512);
  transpose_cast<<<dim3(512 / 32, 2048 / 32), dim3(32, 8), 0, stream>>>(Wv, WqkvT + 2560 * 2048, 2048, 512);
  transpose_cast<<<dim3(2048 / 32, 2048 / 32), dim3(32, 8), 0, stream>>>(Wo, WoT, 2048, 2048);

  gemm_bt<1><<<dim3(3072 / 128, 4096 / 128), 256, 0, stream>>>(Xb, WqkvT, 2048, nullptr, 0, Qn, Kn, Vt);
  // Q scale = (1/sqrt(128)) * log2(e)  -> softmax runs in base-2
  qk_norm<<<(65536 + 16384) / 4, 256, 0, stream>>>(Qn, Kn, 0.12751742f);
  attn<<<512, 256, 0, stream>>>(Qn, Kn, Vt, AO);
  gemm_bt<0><<<dim3(2048 / 128, 4096 / 128), 256, 0, stream>>>(AO, WoT, 2048, out, 2048,
                                                               nullptr, nullptr, nullptr);
}